// Round 6
// baseline (656.525 us; speedup 1.0000x reference)
//
#include <hip/hip_runtime.h>
#include <hip/hip_bf16.h>
#include <math.h>

#define D 64
#define NRBF 32
#define NNODE 128
#define WPB 8
#define NTHREADS (WPB * 64)

// per-wave LDS scratch layout (floats):
// [0,32) rbf ; [32,96) h ; [96,160) w1 ; [160,224) w2 ;
// [224,288) tz ; [288,416) u ; [416,480) tm0 ; [480,608) um1 ; [608,736) um2
#define WS_FLOATS 736

// Intra-wave LDS fence: CDNA waves are 64-lane lockstep, so draining lgkmcnt
// makes this wave's ds_writes visible to its own cross-lane ds_reads.
__device__ __forceinline__ void wave_sync() {
  asm volatile("s_waitcnt lgkmcnt(0)" ::: "memory");
}

__global__ void __launch_bounds__(NTHREADS) so2_msg_kernel(
    const float* __restrict__ node_scalar,
    const float* __restrict__ node_vec,
    const float* __restrict__ node_tensor,
    const float* __restrict__ rbf,
    const float* __restrict__ r_hat,
    const float* __restrict__ amask,
    const float* __restrict__ w_r1,
    const float* __restrict__ b_r1,
    const float* __restrict__ w_r2,
    const float* __restrict__ b_r2,
    const float* __restrict__ w_l0,
    const float* __restrict__ w_l1m0,
    const float* __restrict__ w_l1m1,
    const float* __restrict__ w_l2m0,
    const float* __restrict__ w_l2m1,
    const float* __restrict__ w_l2m2,
    const float* __restrict__ w_out,
    const float* __restrict__ b_out,
    const float* __restrict__ g_s,
    const float* __restrict__ beta_s,
    const float* __restrict__ g_v,
    const float* __restrict__ beta_v,
    const float* __restrict__ g_t,
    const float* __restrict__ beta_t,
    float* __restrict__ out)
{
  __shared__ float ws[WPB][WS_FLOATS];
  __shared__ float ns[D];
  __shared__ float red[9 * WPB * D];
  __shared__ float fin[9 * D];
  __shared__ float tmp64[D];

  const int bi = blockIdx.x;     // b*128 + i
  const int tid = threadIdx.x;
  const int w = tid >> 6;
  const int d = tid & 63;

  if (tid < D) ns[tid] = node_scalar[bi * D + tid];

  float nv[3], nt[5];
#pragma unroll
  for (int q = 0; q < 3; ++q) nv[q] = node_vec[(bi * 3 + q) * D + d];
#pragma unroll
  for (int q = 0; q < 5; ++q) nt[q] = node_tensor[(bi * 5 + q) * D + d];

  float w0sum = 0.f;
  float mv0 = 0.f, mv1 = 0.f, mv2 = 0.f;
  float mt[5] = {0.f, 0.f, 0.f, 0.f, 0.f};

  float* S = ws[w];
  float* Srbf = S;
  float* Sh   = S + 32;
  float* Sw1  = S + 96;
  float* Sw2  = S + 160;
  float* Stz  = S + 224;
  float* Su   = S + 288;
  float* Stm0 = S + 416;
  float* Sum1 = S + 480;
  float* Sum2 = S + 608;

  for (int j = w; j < NNODE; j += WPB) {
    const int e = bi * NNODE + j;
    const float m = amask[e];
    if (m == 0.f) continue;   // wave-uniform branch; no block barriers inside loop

    // ---- stage rbf row ----
    if (d < NRBF) Srbf[d] = rbf[e * NRBF + d];
    wave_sync();

    // ---- h = silu(rbf @ w_r1 + b_r1) ----
    float acc = b_r1[d];
#pragma unroll 8
    for (int r = 0; r < NRBF; ++r)
      acc = fmaf(Srbf[r], w_r1[r * D + d], acc);
    const float hval = acc / (1.f + expf(-acc));
    Sh[d] = hval;
    wave_sync();

    // ---- w0/w1/w2 = (h @ w_r2 + b_r2) * mask ----
    float a0 = b_r2[d];
    float a1 = b_r2[D + d];
    float a2 = b_r2[2 * D + d];
#pragma unroll 4
    for (int k = 0; k < D; ++k) {
      const float hk = Sh[k];
      const float* wr = w_r2 + k * 3 * D;
      a0 = fmaf(hk, wr[d], a0);
      a1 = fmaf(hk, wr[D + d], a1);
      a2 = fmaf(hk, wr[2 * D + d], a2);
    }
    a0 *= m; a1 *= m; a2 *= m;
    w0sum += a0;
    Sw1[d] = a1;
    Sw2[d] = a2;

    // ---- rotation R from r_hat (per-lane redundant) ----
    const float rx = r_hat[e * 3 + 0];
    const float ry = r_hat[e * 3 + 1];
    const float rz = r_hat[e * 3 + 2];
    const bool use_x = fabsf(rz) > 0.9f;
    const float fx = use_x ? 0.f : 1.f;
    const float fz = use_x ? 1.f : 0.f;
    const float proj = fx * rx + fz * rz;
    float x0 = fx - proj * rx;
    float x1 =    - proj * ry;
    float x2 = fz - proj * rz;
    const float invn = 1.f / (sqrtf(x0 * x0 + x1 * x1 + x2 * x2) + 1e-8f);
    x0 *= invn; x1 *= invn; x2 *= invn;
    const float y0 = ry * x2 - rz * x1;
    const float y1 = rz * x0 - rx * x2;
    const float y2 = rx * x1 - ry * x0;
    // R[p][q], columns = (x_norm, y, r_hat)
    const float R[3][3] = {{x0, y0, rx}, {x1, y1, ry}, {x2, y2, rz}};

    // ---- Wigner D (l=2) from closed form: D2[c][v] = sum_k sh2_c(R V_k) Ainv[k][v] ----
    float D2[5][5];
    {
      const float a = 0.70710678118654752f;
      float Rv[5][3];
      Rv[0][0] = x0; Rv[0][1] = x1; Rv[0][2] = x2;            // R @ ex  = col0
      Rv[2][0] = rx; Rv[2][1] = ry; Rv[2][2] = rz;            // R @ ez  = col2
      Rv[1][0] = a * (y0 + rx); Rv[1][1] = a * (y1 + ry); Rv[1][2] = a * (y2 + rz);
      Rv[3][0] = a * (x0 + y0); Rv[3][1] = a * (x1 + y1); Rv[3][2] = a * (x2 + y2);
      Rv[4][0] = a * (x0 + rx); Rv[4][1] = a * (x1 + ry); Rv[4][2] = a * (x2 + rz);
      float Ap[5][5];
      const float s3 = 1.7320508075688772f;
#pragma unroll
      for (int k = 0; k < 5; ++k) {
        const float X = Rv[k][0], Y = Rv[k][1], Z = Rv[k][2];
        Ap[k][0] = s3 * X * Z;
        Ap[k][1] = s3 * X * Y;
        Ap[k][2] = Y * Y - 0.5f * (X * X + Z * Z);
        Ap[k][3] = s3 * Y * Z;
        Ap[k][4] = 0.5f * s3 * (Z * Z - X * X);
      }
      const float t = 0.57735026918962576f;   // 1/sqrt(3)
#pragma unroll
      for (int c = 0; c < 5; ++c) {
        D2[c][0] = t * (2.f * Ap[4][c] - Ap[0][c] - Ap[2][c]);
        D2[c][1] = t * (Ap[2][c] + 2.f * Ap[3][c]);
        D2[c][2] = -(Ap[0][c] + Ap[2][c]);
        D2[c][3] = t * (Ap[0][c] + 2.f * Ap[1][c]);
        D2[c][4] = t * (Ap[2][c] - Ap[0][c]);
      }
    }
    wave_sync();   // Sw1/Sw2 now visible

    // ---- rotate node features into local frame ----
    float vl[3], tl[5];
#pragma unroll
    for (int p = 0; p < 3; ++p)
      vl[p] = R[p][0] * nv[0] + R[p][1] * nv[1] + R[p][2] * nv[2];
#pragma unroll
    for (int p = 0; p < 5; ++p) {
      float s = 0.f;
#pragma unroll
      for (int q = 0; q < 5; ++q) s = fmaf(D2[p][q], nt[q], s);
      tl[p] = s;
    }

    // ---- stage elementwise-scaled vectors (note repeat(w,2) semantics: w[k>>1]) ----
    Stz[d]       = vl[2] * a1;
    Su[d]        = vl[0] * Sw1[d >> 1];
    Su[D + d]    = vl[1] * Sw1[32 + (d >> 1)];
    Stm0[d]      = tl[2] * a2;
    Sum1[d]      = tl[1] * Sw2[d >> 1];
    Sum1[D + d]  = tl[3] * Sw2[32 + (d >> 1)];
    Sum2[d]      = tl[0] * Sw2[d >> 1];
    Sum2[D + d]  = tl[4] * Sw2[32 + (d >> 1)];
    wave_sync();

    // ---- channel-mix matvecs ----
    float zo = 0.f, q0 = 0.f;
#pragma unroll 4
    for (int k = 0; k < D; ++k) {
      zo = fmaf(Stz[k],  w_l1m0[k * D + d], zo);
      q0 = fmaf(Stm0[k], w_l2m0[k * D + d], q0);
    }
    float xo0 = 0.f, xo1 = 0.f, q10 = 0.f, q11 = 0.f, q20 = 0.f, q21 = 0.f;
#pragma unroll 4
    for (int k = 0; k < 2 * D; ++k) {
      const float uk = Su[k], u1k = Sum1[k], u2k = Sum2[k];
      const int row = k * 2 * D;
      xo0 = fmaf(uk,  w_l1m1[row + d], xo0);
      xo1 = fmaf(uk,  w_l1m1[row + D + d], xo1);
      q10 = fmaf(u1k, w_l2m1[row + d], q10);
      q11 = fmaf(u1k, w_l2m1[row + D + d], q11);
      q20 = fmaf(u2k, w_l2m2[row + d], q20);
      q21 = fmaf(u2k, w_l2m2[row + D + d], q21);
    }

    // ---- rotate messages back to global frame, accumulate over j ----
    mv0 += R[0][0] * xo0 + R[1][0] * xo1 + R[2][0] * zo;
    mv1 += R[0][1] * xo0 + R[1][1] * xo1 + R[2][1] * zo;
    mv2 += R[0][2] * xo0 + R[1][2] * xo1 + R[2][2] * zo;
    const float mtl[5] = {q20, q10, q0, q11, q21};
#pragma unroll
    for (int p = 0; p < 5; ++p) {
      float s = mt[p];
#pragma unroll
      for (int q = 0; q < 5; ++q) s = fmaf(D2[q][p], mtl[q], s);
      mt[p] = s;
    }
    wave_sync();   // all LDS reads done before next iteration overwrites scratch
  }

  // ---- cross-wave reduction ----
  __syncthreads();
  red[(0 * WPB + w) * D + d] = w0sum;
  red[(1 * WPB + w) * D + d] = mv0;
  red[(2 * WPB + w) * D + d] = mv1;
  red[(3 * WPB + w) * D + d] = mv2;
#pragma unroll
  for (int c = 0; c < 5; ++c) red[((4 + c) * WPB + w) * D + d] = mt[c];
  __syncthreads();
  for (int idx = tid; idx < 9 * D; idx += NTHREADS) {
    const int a = idx >> 6, dd = idx & 63;
    float s = 0.f;
#pragma unroll
    for (int ww = 0; ww < WPB; ++ww) s += red[(a * WPB + ww) * D + dd];
    fin[a * D + dd] = s;
  }
  __syncthreads();

  // ---- msg_s epilogue: (node_scalar @ w_l0) * w0sum, then @ w_out + b_out ----
  if (tid < D) {
    float s0 = 0.f;
    for (int k = 0; k < D; ++k) s0 = fmaf(ns[k], w_l0[k * D + tid], s0);
    tmp64[tid] = s0 * fin[tid];
  }
  __syncthreads();
  if (tid < D) {
    float pre = b_out[tid];
    for (int k = 0; k < D; ++k) pre = fmaf(tmp64[k], w_out[k * D + tid], pre);
    fin[tid] = pre;
  }
  __syncthreads();

  // ---- LayerNorm over 9 rows (1 scalar, 3 vector, 5 tensor), write f32 ----
  for (int r = w; r < 9; r += WPB) {
    const float x = fin[r * D + d];
    float s = x;
#pragma unroll
    for (int off = 32; off > 0; off >>= 1) s += __shfl_xor(s, off, 64);
    const float mu = s * (1.f / 64.f);
    const float xm = x - mu;
    float v = xm * xm;
#pragma unroll
    for (int off = 32; off > 0; off >>= 1) v += __shfl_xor(v, off, 64);
    const float var = v * (1.f / 64.f);
    const float rstd = rsqrtf(var + 1e-5f);
    float g, be;
    int off_out;
    if (r == 0)      { g = g_s[d]; be = beta_s[d]; off_out = bi * D + d; }
    else if (r < 4)  { g = g_v[d]; be = beta_v[d]; off_out = 16384 + (bi * 3 + (r - 1)) * D + d; }
    else             { g = g_t[d]; be = beta_t[d]; off_out = 65536 + (bi * 5 + (r - 4)) * D + d; }
    out[off_out] = xm * rstd * g + be;
  }
}

extern "C" void kernel_launch(void* const* d_in, const int* in_sizes, int n_in,
                              void* d_out, int out_size, void* d_ws, size_t ws_size,
                              hipStream_t stream) {
  const float* p[24];
  for (int i = 0; i < 24; ++i) p[i] = (const float*)d_in[i];
  so2_msg_kernel<<<dim3(256), dim3(NTHREADS), 0, stream>>>(
      p[0], p[1], p[2], p[3], p[4], p[5], p[6], p[7], p[8], p[9],
      p[10], p[11], p[12], p[13], p[14], p[15], p[16], p[17], p[18], p[19],
      p[20], p[21], p[22], p[23],
      (float*)d_out);
}

// Round 7
// 374.719 us; speedup vs baseline: 1.7520x; 1.7520x over previous
//
#include <hip/hip_runtime.h>
#include <hip/hip_bf16.h>
#include <math.h>

#define D 64
#define NRBF 32
#define NNODE 128
#define WPB 8
#define NTHREADS (WPB * 64)

// per-wave LDS scratch layout (floats):
// [0,32) rbf ; [32,96) h ; [96,160) w1 ; [160,224) w2 ;
// [224,288) tz ; [288,416) u ; [416,480) tm0 ; [480,608) um1 ; [608,736) um2
#define WS_FLOATS 736

// Intra-wave LDS fence: CDNA waves are 64-lane lockstep, so draining lgkmcnt
// makes this wave's ds_writes visible to its own cross-lane ds_reads.
__device__ __forceinline__ void wave_sync() {
  asm volatile("s_waitcnt lgkmcnt(0)" ::: "memory");
}

// Kernel 1: per-(b,i,j-chunk) message accumulation -> partial sums in d_ws.
// grid = 256 * jsplit blocks; block (bi, split) handles j in [split*JCH, (split+1)*JCH).
__global__ void __launch_bounds__(NTHREADS) so2_partial_kernel(
    const float* __restrict__ node_vec,
    const float* __restrict__ node_tensor,
    const float* __restrict__ rbf,
    const float* __restrict__ r_hat,
    const float* __restrict__ amask,
    const float* __restrict__ w_r1,
    const float* __restrict__ b_r1,
    const float* __restrict__ w_r2,
    const float* __restrict__ b_r2,
    const float* __restrict__ w_l1m0,
    const float* __restrict__ w_l1m1,
    const float* __restrict__ w_l2m0,
    const float* __restrict__ w_l2m1,
    const float* __restrict__ w_l2m2,
    float* __restrict__ pws,
    int jsplit)
{
  __shared__ float smem[WPB * WS_FLOATS];   // 23.5 KB; reused as reduction buf after j-loop

  const int bid = blockIdx.x;
  const int bi = bid / jsplit;          // b*128 + i
  const int split = bid - bi * jsplit;
  const int tid = threadIdx.x;
  const int w = tid >> 6;
  const int d = tid & 63;

  float nv[3], nt[5];
#pragma unroll
  for (int q = 0; q < 3; ++q) nv[q] = node_vec[(bi * 3 + q) * D + d];
#pragma unroll
  for (int q = 0; q < 5; ++q) nt[q] = node_tensor[(bi * 5 + q) * D + d];

  float w0sum = 0.f;
  float mv0 = 0.f, mv1 = 0.f, mv2 = 0.f;
  float mt[5] = {0.f, 0.f, 0.f, 0.f, 0.f};

  float* S = smem + w * WS_FLOATS;
  float* Srbf = S;
  float* Sh   = S + 32;
  float* Sw1  = S + 96;
  float* Sw2  = S + 160;
  float* Stz  = S + 224;
  float* Su   = S + 288;
  float* Stm0 = S + 416;
  float* Sum1 = S + 480;
  float* Sum2 = S + 608;

  const int JCH = NNODE / jsplit;
  const int jlo = split * JCH, jhi = jlo + JCH;

  for (int j = jlo + w; j < jhi; j += WPB) {
    const int e = bi * NNODE + j;
    const float m = amask[e];
    if (m == 0.f) continue;   // wave-uniform branch; no block barriers inside loop

    // ---- stage rbf row ----
    if (d < NRBF) Srbf[d] = rbf[e * NRBF + d];
    wave_sync();

    // ---- h = silu(rbf @ w_r1 + b_r1) ----
    float acc = b_r1[d];
#pragma unroll 8
    for (int r = 0; r < NRBF; ++r)
      acc = fmaf(Srbf[r], w_r1[r * D + d], acc);
    const float hval = acc / (1.f + expf(-acc));
    Sh[d] = hval;
    wave_sync();

    // ---- w0/w1/w2 = (h @ w_r2 + b_r2) * mask ----
    float a0 = b_r2[d];
    float a1 = b_r2[D + d];
    float a2 = b_r2[2 * D + d];
#pragma unroll 8
    for (int k = 0; k < D; ++k) {
      const float hk = Sh[k];
      const float* wr = w_r2 + k * 3 * D;
      a0 = fmaf(hk, wr[d], a0);
      a1 = fmaf(hk, wr[D + d], a1);
      a2 = fmaf(hk, wr[2 * D + d], a2);
    }
    a0 *= m; a1 *= m; a2 *= m;
    w0sum += a0;
    Sw1[d] = a1;
    Sw2[d] = a2;

    // ---- rotation R from r_hat (per-lane redundant) ----
    const float rx = r_hat[e * 3 + 0];
    const float ry = r_hat[e * 3 + 1];
    const float rz = r_hat[e * 3 + 2];
    const bool use_x = fabsf(rz) > 0.9f;
    const float fx = use_x ? 0.f : 1.f;
    const float fz = use_x ? 1.f : 0.f;
    const float proj = fx * rx + fz * rz;
    float x0 = fx - proj * rx;
    float x1 =    - proj * ry;
    float x2 = fz - proj * rz;
    const float invn = 1.f / (sqrtf(x0 * x0 + x1 * x1 + x2 * x2) + 1e-8f);
    x0 *= invn; x1 *= invn; x2 *= invn;
    const float y0 = ry * x2 - rz * x1;
    const float y1 = rz * x0 - rx * x2;
    const float y2 = rx * x1 - ry * x0;
    // R[p][q], columns = (x_norm, y, r_hat)
    const float R[3][3] = {{x0, y0, rx}, {x1, y1, ry}, {x2, y2, rz}};

    // ---- Wigner D (l=2) from closed form: D2[c][v] = sum_k sh2_c(R V_k) Ainv[k][v] ----
    float D2[5][5];
    {
      const float a = 0.70710678118654752f;
      float Rv[5][3];
      Rv[0][0] = x0; Rv[0][1] = x1; Rv[0][2] = x2;            // R @ ex  = col0
      Rv[2][0] = rx; Rv[2][1] = ry; Rv[2][2] = rz;            // R @ ez  = col2
      Rv[1][0] = a * (y0 + rx); Rv[1][1] = a * (y1 + ry); Rv[1][2] = a * (y2 + rz);
      Rv[3][0] = a * (x0 + y0); Rv[3][1] = a * (x1 + y1); Rv[3][2] = a * (x2 + y2);
      Rv[4][0] = a * (x0 + rx); Rv[4][1] = a * (x1 + ry); Rv[4][2] = a * (x2 + rz);
      float Ap[5][5];
      const float s3 = 1.7320508075688772f;
#pragma unroll
      for (int k = 0; k < 5; ++k) {
        const float X = Rv[k][0], Y = Rv[k][1], Z = Rv[k][2];
        Ap[k][0] = s3 * X * Z;
        Ap[k][1] = s3 * X * Y;
        Ap[k][2] = Y * Y - 0.5f * (X * X + Z * Z);
        Ap[k][3] = s3 * Y * Z;
        Ap[k][4] = 0.5f * s3 * (Z * Z - X * X);
      }
      const float t = 0.57735026918962576f;   // 1/sqrt(3)
#pragma unroll
      for (int c = 0; c < 5; ++c) {
        D2[c][0] = t * (2.f * Ap[4][c] - Ap[0][c] - Ap[2][c]);
        D2[c][1] = t * (Ap[2][c] + 2.f * Ap[3][c]);
        D2[c][2] = -(Ap[0][c] + Ap[2][c]);
        D2[c][3] = t * (Ap[0][c] + 2.f * Ap[1][c]);
        D2[c][4] = t * (Ap[2][c] - Ap[0][c]);
      }
    }
    wave_sync();   // Sw1/Sw2 now visible

    // ---- rotate node features into local frame ----
    float vl[3], tl[5];
#pragma unroll
    for (int p = 0; p < 3; ++p)
      vl[p] = R[p][0] * nv[0] + R[p][1] * nv[1] + R[p][2] * nv[2];
#pragma unroll
    for (int p = 0; p < 5; ++p) {
      float s = 0.f;
#pragma unroll
      for (int q = 0; q < 5; ++q) s = fmaf(D2[p][q], nt[q], s);
      tl[p] = s;
    }

    // ---- stage elementwise-scaled vectors (note repeat(w,2) semantics: w[k>>1]) ----
    Stz[d]       = vl[2] * a1;
    Su[d]        = vl[0] * Sw1[d >> 1];
    Su[D + d]    = vl[1] * Sw1[32 + (d >> 1)];
    Stm0[d]      = tl[2] * a2;
    Sum1[d]      = tl[1] * Sw2[d >> 1];
    Sum1[D + d]  = tl[3] * Sw2[32 + (d >> 1)];
    Sum2[d]      = tl[0] * Sw2[d >> 1];
    Sum2[D + d]  = tl[4] * Sw2[32 + (d >> 1)];
    wave_sync();

    // ---- channel-mix matvecs ----
    float zo = 0.f, q0 = 0.f;
#pragma unroll 8
    for (int k = 0; k < D; ++k) {
      zo = fmaf(Stz[k],  w_l1m0[k * D + d], zo);
      q0 = fmaf(Stm0[k], w_l2m0[k * D + d], q0);
    }
    float xo0 = 0.f, xo1 = 0.f, q10 = 0.f, q11 = 0.f, q20 = 0.f, q21 = 0.f;
#pragma unroll 8
    for (int k = 0; k < 2 * D; ++k) {
      const float uk = Su[k], u1k = Sum1[k], u2k = Sum2[k];
      const int row = k * 2 * D;
      xo0 = fmaf(uk,  w_l1m1[row + d], xo0);
      xo1 = fmaf(uk,  w_l1m1[row + D + d], xo1);
      q10 = fmaf(u1k, w_l2m1[row + d], q10);
      q11 = fmaf(u1k, w_l2m1[row + D + d], q11);
      q20 = fmaf(u2k, w_l2m2[row + d], q20);
      q21 = fmaf(u2k, w_l2m2[row + D + d], q21);
    }

    // ---- rotate messages back to global frame, accumulate over j ----
    mv0 += R[0][0] * xo0 + R[1][0] * xo1 + R[2][0] * zo;
    mv1 += R[0][1] * xo0 + R[1][1] * xo1 + R[2][1] * zo;
    mv2 += R[0][2] * xo0 + R[1][2] * xo1 + R[2][2] * zo;
    const float mtl[5] = {q20, q10, q0, q11, q21};
#pragma unroll
    for (int p = 0; p < 5; ++p) {
      float s = mt[p];
#pragma unroll
      for (int q = 0; q < 5; ++q) s = fmaf(D2[q][p], mtl[q], s);
      mt[p] = s;
    }
    wave_sync();   // all LDS reads done before next iteration overwrites scratch
  }

  // ---- cross-wave reduction into partial buffer (reuse smem) ----
  __syncthreads();
  float* red = smem;
  red[(0 * WPB + w) * D + d] = w0sum;
  red[(1 * WPB + w) * D + d] = mv0;
  red[(2 * WPB + w) * D + d] = mv1;
  red[(3 * WPB + w) * D + d] = mv2;
#pragma unroll
  for (int c = 0; c < 5; ++c) red[((4 + c) * WPB + w) * D + d] = mt[c];
  __syncthreads();
  float* pout = pws + bid * (9 * D);
  for (int idx = tid; idx < 9 * D; idx += NTHREADS) {
    const int a = idx >> 6, dd = idx & 63;
    float s = 0.f;
#pragma unroll
    for (int ww = 0; ww < WPB; ++ww) s += red[(a * WPB + ww) * D + dd];
    pout[idx] = s;
  }
}

// Kernel 2: reduce jsplit partials, scalar-path epilogue, LayerNorm, write out.
// grid = 256 blocks x 64 threads (one wave per (b,i)).
__global__ void __launch_bounds__(64) so2_epilogue_kernel(
    const float* __restrict__ node_scalar,
    const float* __restrict__ w_l0,
    const float* __restrict__ w_out,
    const float* __restrict__ b_out,
    const float* __restrict__ g_s,
    const float* __restrict__ beta_s,
    const float* __restrict__ g_v,
    const float* __restrict__ beta_v,
    const float* __restrict__ g_t,
    const float* __restrict__ beta_t,
    const float* __restrict__ pws,
    int jsplit,
    float* __restrict__ out)
{
  __shared__ float sf[9 * D];
  __shared__ float sns[D];
  __shared__ float stmp[D];

  const int bi = blockIdx.x;
  const int d = threadIdx.x;

  float f0 = 0.f;
#pragma unroll
  for (int a = 0; a < 9; ++a) {
    float s = 0.f;
    for (int sp = 0; sp < jsplit; ++sp)
      s += pws[((bi * jsplit + sp) * 9 + a) * D + d];
    sf[a * D + d] = s;
    if (a == 0) f0 = s;
  }
  sns[d] = node_scalar[bi * D + d];
  __syncthreads();

  // (node_scalar @ w_l0) * w0sum
  float s0 = 0.f;
#pragma unroll 8
  for (int k = 0; k < D; ++k) s0 = fmaf(sns[k], w_l0[k * D + d], s0);
  stmp[d] = s0 * f0;
  __syncthreads();

  float pre = b_out[d];
#pragma unroll 8
  for (int k = 0; k < D; ++k) pre = fmaf(stmp[k], w_out[k * D + d], pre);

  // LayerNorm over 9 rows (row 0 = scalar msg after w_out; rows 1-3 vec; 4-8 tensor)
  for (int r = 0; r < 9; ++r) {
    const float x = (r == 0) ? pre : sf[r * D + d];
    float s = x;
#pragma unroll
    for (int off = 32; off > 0; off >>= 1) s += __shfl_xor(s, off, 64);
    const float mu = s * (1.f / 64.f);
    const float xm = x - mu;
    float v = xm * xm;
#pragma unroll
    for (int off = 32; off > 0; off >>= 1) v += __shfl_xor(v, off, 64);
    const float var = v * (1.f / 64.f);
    const float rstd = rsqrtf(var + 1e-5f);
    float g, be;
    int off_out;
    if (r == 0)      { g = g_s[d]; be = beta_s[d]; off_out = bi * D + d; }
    else if (r < 4)  { g = g_v[d]; be = beta_v[d]; off_out = 16384 + (bi * 3 + (r - 1)) * D + d; }
    else             { g = g_t[d]; be = beta_t[d]; off_out = 65536 + (bi * 5 + (r - 4)) * D + d; }
    out[off_out] = xm * rstd * g + be;
  }
}

extern "C" void kernel_launch(void* const* d_in, const int* in_sizes, int n_in,
                              void* d_out, int out_size, void* d_ws, size_t ws_size,
                              hipStream_t stream) {
  const float* p[24];
  for (int i = 0; i < 24; ++i) p[i] = (const float*)d_in[i];
  float* pws = (float*)d_ws;

  int jsplit = 4;
  while (jsplit > 1 && ws_size < (size_t)(256 * jsplit) * 9 * D * sizeof(float))
    jsplit >>= 1;

  so2_partial_kernel<<<dim3(256 * jsplit), dim3(NTHREADS), 0, stream>>>(
      p[1], p[2], p[3], p[4], p[5], p[6], p[7], p[8], p[9],
      p[11], p[12], p[13], p[14], p[15],
      pws, jsplit);

  so2_epilogue_kernel<<<dim3(256), dim3(64), 0, stream>>>(
      p[0], p[10], p[16], p[17], p[18], p[19], p[20], p[21], p[22], p[23],
      pws, jsplit, (float*)d_out);
}

// Round 8
// 163.739 us; speedup vs baseline: 4.0096x; 2.2885x over previous
//
#include <hip/hip_runtime.h>
#include <hip/hip_bf16.h>
#include <math.h>

#define D 64
#define NRBF 32
#define NNODE 128
#define WPB 8
#define NTHREADS (WPB * 64)

// per-wave LDS scratch (floats): Srbf 64 | Sh 128 | Stz 128 | Stm0 128 |
// Su 256 | Sum1 256 | Sum2 256 | SD2 64  => 1280 floats = 5 KB/wave
#define WS_FLOATS 1280

__device__ __forceinline__ void wave_sync() {
  asm volatile("s_waitcnt lgkmcnt(0)" ::: "memory");
}

// Front-end for one edge: rotation R, Wigner D2 (stored to LDS), rotate node
// features into local frame, stage masked/scaled matvec inputs. A1/A2 are the
// masked per-channel gate values (w1,w2) for this edge.
#define FRONTEND_EDGE(SLOT, EDGE, A1, A2, R00,R01,R02,R10,R11,R12,R20,R21,R22) do { \
  const float rx = r_hat[(EDGE)*3+0], ry = r_hat[(EDGE)*3+1], rz = r_hat[(EDGE)*3+2]; \
  const bool use_x = fabsf(rz) > 0.9f; \
  const float fx = use_x ? 0.f : 1.f; \
  const float fz = use_x ? 1.f : 0.f; \
  const float proj = fx*rx + fz*rz; \
  float x0 = fx - proj*rx, x1 = -proj*ry, x2 = fz - proj*rz; \
  const float invn = 1.f/(sqrtf(x0*x0+x1*x1+x2*x2)+1e-8f); \
  x0*=invn; x1*=invn; x2*=invn; \
  const float y0 = ry*x2 - rz*x1, y1 = rz*x0 - rx*x2, y2 = rx*x1 - ry*x0; \
  R00=x0; R01=y0; R02=rx; R10=x1; R11=y1; R12=ry; R20=x2; R21=y2; R22=rz; \
  float D2m[5][5]; \
  { const float aa = 0.70710678118654752f; \
    float Rv[5][3]; \
    Rv[0][0]=x0; Rv[0][1]=x1; Rv[0][2]=x2; \
    Rv[2][0]=rx; Rv[2][1]=ry; Rv[2][2]=rz; \
    Rv[1][0]=aa*(y0+rx); Rv[1][1]=aa*(y1+ry); Rv[1][2]=aa*(y2+rz); \
    Rv[3][0]=aa*(x0+y0); Rv[3][1]=aa*(x1+y1); Rv[3][2]=aa*(x2+y2); \
    Rv[4][0]=aa*(x0+rx); Rv[4][1]=aa*(x1+ry); Rv[4][2]=aa*(x2+rz); \
    float Ap[5][5]; \
    const float s3 = 1.7320508075688772f; \
    _Pragma("unroll") \
    for (int k5=0;k5<5;++k5){ \
      const float X=Rv[k5][0], Y=Rv[k5][1], Z=Rv[k5][2]; \
      Ap[k5][0]=s3*X*Z; Ap[k5][1]=s3*X*Y; Ap[k5][2]=Y*Y-0.5f*(X*X+Z*Z); \
      Ap[k5][3]=s3*Y*Z; Ap[k5][4]=0.5f*s3*(Z*Z-X*X); } \
    const float tt = 0.57735026918962576f; \
    _Pragma("unroll") \
    for (int c=0;c<5;++c){ \
      D2m[c][0]=tt*(2.f*Ap[4][c]-Ap[0][c]-Ap[2][c]); \
      D2m[c][1]=tt*(Ap[2][c]+2.f*Ap[3][c]); \
      D2m[c][2]=-(Ap[0][c]+Ap[2][c]); \
      D2m[c][3]=tt*(Ap[0][c]+2.f*Ap[1][c]); \
      D2m[c][4]=tt*(Ap[2][c]-Ap[0][c]); } } \
  _Pragma("unroll") \
  for (int c=0;c<5;++c){ \
    _Pragma("unroll") \
    for (int v=0;v<5;++v){ if (d == c*5+v) SD2[(SLOT)*32 + c*5+v] = D2m[c][v]; } } \
  const float vl0 = R00*nv0 + R01*nv1 + R02*nv2; \
  const float vl1 = R10*nv0 + R11*nv1 + R12*nv2; \
  const float vl2 = R20*nv0 + R21*nv1 + R22*nv2; \
  float tl[5]; \
  _Pragma("unroll") \
  for (int p=0;p<5;++p) \
    tl[p] = D2m[p][0]*nt0 + D2m[p][1]*nt1 + D2m[p][2]*nt2 + D2m[p][3]*nt3 + D2m[p][4]*nt4; \
  const float a1lo = __shfl((A1), d>>1), a1hi = __shfl((A1), 32+(d>>1)); \
  const float a2lo = __shfl((A2), d>>1), a2hi = __shfl((A2), 32+(d>>1)); \
  Stz [(SLOT)*64 + d]       = vl2   * (A1); \
  Su  [(SLOT)*128 + d]      = vl0   * a1lo; \
  Su  [(SLOT)*128 + 64 + d] = vl1   * a1hi; \
  Stm0[(SLOT)*64 + d]       = tl[2] * (A2); \
  Sum1[(SLOT)*128 + d]      = tl[1] * a2lo; \
  Sum1[(SLOT)*128 + 64 + d] = tl[3] * a2hi; \
  Sum2[(SLOT)*128 + d]      = tl[0] * a2lo; \
  Sum2[(SLOT)*128 + 64 + d] = tl[4] * a2hi; \
} while(0)

// Rotate local-frame message back to global frame and accumulate.
#define BACKROT_EDGE(SLOT, R00,R01,R02,R10,R11,R12,R20,R21,R22, XO0,XO1,ZO, Q2A,Q1A,Q0A,Q1B,Q2B) do { \
  mv0 += (R00)*(XO0) + (R10)*(XO1) + (R20)*(ZO); \
  mv1 += (R01)*(XO0) + (R11)*(XO1) + (R21)*(ZO); \
  mv2 += (R02)*(XO0) + (R12)*(XO1) + (R22)*(ZO); \
  const float mtl_[5] = {(Q2A),(Q1A),(Q0A),(Q1B),(Q2B)}; \
  _Pragma("unroll") \
  for (int p=0;p<5;++p){ float s_=mt[p]; \
    _Pragma("unroll") \
    for (int q=0;q<5;++q) s_ = fmaf(SD2[(SLOT)*32 + q*5+p], mtl_[q], s_); \
    mt[p]=s_; } \
} while(0)

__global__ void __launch_bounds__(NTHREADS, 4) so2_partial_kernel(
    const float* __restrict__ node_vec,
    const float* __restrict__ node_tensor,
    const float* __restrict__ rbf,
    const float* __restrict__ r_hat,
    const float* __restrict__ amask,
    const float* __restrict__ w_r1,
    const float* __restrict__ b_r1,
    const float* __restrict__ w_r2,
    const float* __restrict__ b_r2,
    const float* __restrict__ w_l1m0,
    const float* __restrict__ w_l1m1,
    const float* __restrict__ w_l2m0,
    const float* __restrict__ w_l2m1,
    const float* __restrict__ w_l2m2,
    float* __restrict__ pws,
    int jsplit)
{
  __shared__ float smem[WPB * WS_FLOATS];
  __shared__ int actlist[NNODE];
  __shared__ int s_nact;

  const int bid = blockIdx.x;
  const int bi = bid / jsplit;
  const int split = bid - bi * jsplit;
  const int tid = threadIdx.x;
  const int w = tid >> 6;
  const int d = tid & 63;

  const int JCH = NNODE / jsplit;
  const int jlo = split * JCH;

  // ---- deterministic ballot-compaction of active edges (wave 0) ----
  if (w == 0) {
    int n = 0;
    for (int chunk = 0; chunk < JCH; chunk += 64) {
      const int jj = chunk + d;
      const bool act = (jj < JCH) && (amask[bi * NNODE + jlo + jj] != 0.f);
      const unsigned long long bal = __ballot(act);
      if (act) actlist[n + __popcll(bal & ((1ULL << d) - 1ULL))] = jlo + jj;
      n += (int)__popcll(bal);
    }
    if (d == 0) s_nact = n;
  }

  const float nv0 = node_vec[(bi * 3 + 0) * D + d];
  const float nv1 = node_vec[(bi * 3 + 1) * D + d];
  const float nv2 = node_vec[(bi * 3 + 2) * D + d];
  const float nt0 = node_tensor[(bi * 5 + 0) * D + d];
  const float nt1 = node_tensor[(bi * 5 + 1) * D + d];
  const float nt2 = node_tensor[(bi * 5 + 2) * D + d];
  const float nt3 = node_tensor[(bi * 5 + 3) * D + d];
  const float nt4 = node_tensor[(bi * 5 + 4) * D + d];

  float w0sum = 0.f;
  float mv0 = 0.f, mv1 = 0.f, mv2 = 0.f;
  float mt[5] = {0.f, 0.f, 0.f, 0.f, 0.f};

  float* S    = smem + w * WS_FLOATS;
  float* Srbf = S;            // [2][32]
  float* Sh   = S + 64;       // [2][64]
  float* Stz  = S + 192;      // [2][64]
  float* Stm0 = S + 320;      // [2][64]
  float* Su   = S + 448;      // [2][128]
  float* Sum1 = S + 704;      // [2][128]
  float* Sum2 = S + 960;      // [2][128]
  float* SD2  = S + 1216;     // [2][32] (25 used)

  __syncthreads();
  const int nact = s_nact;

  for (int base = 2 * w; base < nact; base += 2 * WPB) {
    const int j0 = actlist[base];
    const bool has2 = (base + 1) < nact;
    const int j1 = has2 ? actlist[base + 1] : j0;
    const int e0 = bi * NNODE + j0;
    const int e1 = bi * NNODE + j1;
    const float m0v = amask[e0];
    const float m1v = has2 ? amask[e1] : 0.f;   // dup edge fully zeroed

    // ---- stage both rbf rows (lane-split) ----
    Srbf[d] = rbf[(d < 32) ? (e0 * NRBF + d) : (e1 * NRBF + d - 32)];
    wave_sync();

    // ---- h = silu(rbf @ w_r1 + b_r1), both edges, shared weight loads ----
    float acc0 = b_r1[d];
    float acc1 = acc0;
#pragma unroll 8
    for (int r = 0; r < NRBF; ++r) {
      const float wv = w_r1[r * D + d];
      acc0 = fmaf(Srbf[r], wv, acc0);
      acc1 = fmaf(Srbf[32 + r], wv, acc1);
    }
    Sh[d]      = acc0 / (1.f + expf(-acc0));
    Sh[64 + d] = acc1 / (1.f + expf(-acc1));
    wave_sync();

    // ---- w0/w1/w2 for both edges, shared weight loads ----
    float a00 = b_r2[d], a10 = b_r2[D + d], a20 = b_r2[2 * D + d];
    float a01 = a00, a11 = a10, a21 = a20;
#pragma unroll 4
    for (int k = 0; k < D; ++k) {
      const float hk0 = Sh[k], hk1 = Sh[64 + k];
      const float* wr = w_r2 + k * 3 * D;
      const float wv0 = wr[d], wv1 = wr[D + d], wv2 = wr[2 * D + d];
      a00 = fmaf(hk0, wv0, a00); a01 = fmaf(hk1, wv0, a01);
      a10 = fmaf(hk0, wv1, a10); a11 = fmaf(hk1, wv1, a11);
      a20 = fmaf(hk0, wv2, a20); a21 = fmaf(hk1, wv2, a21);
    }
    a00 *= m0v; a10 *= m0v; a20 *= m0v;
    a01 *= m1v; a11 *= m1v; a21 *= m1v;
    w0sum += a00 + a01;

    // ---- per-edge front-end (rotation, Wigner, local rotate, staging) ----
    float Ra00,Ra01,Ra02,Ra10,Ra11,Ra12,Ra20,Ra21,Ra22;
    float Rb00,Rb01,Rb02,Rb10,Rb11,Rb12,Rb20,Rb21,Rb22;
    FRONTEND_EDGE(0, e0, a10, a20, Ra00,Ra01,Ra02,Ra10,Ra11,Ra12,Ra20,Ra21,Ra22);
    FRONTEND_EDGE(1, e1, a11, a21, Rb00,Rb01,Rb02,Rb10,Rb11,Rb12,Rb20,Rb21,Rb22);
    wave_sync();

    // ---- channel-mix matvecs, both edges share every weight load ----
    float zo0 = 0.f, zo1 = 0.f, p00 = 0.f, p01 = 0.f;
#pragma unroll 8
    for (int k = 0; k < D; ++k) {
      const float wa = w_l1m0[k * D + d], wb = w_l2m0[k * D + d];
      zo0 = fmaf(Stz[k],       wa, zo0);
      zo1 = fmaf(Stz[64 + k],  wa, zo1);
      p00 = fmaf(Stm0[k],      wb, p00);
      p01 = fmaf(Stm0[64 + k], wb, p01);
    }
    float xo00=0.f,xo10=0.f,q100=0.f,q110=0.f,q200=0.f,q210=0.f;
    float xo01=0.f,xo11=0.f,q101=0.f,q111=0.f,q201=0.f,q211=0.f;
#pragma unroll 4
    for (int k = 0; k < 2 * D; ++k) {
      const int row = k * 2 * D;
      const float wv0 = w_l1m1[row + d], wv1 = w_l1m1[row + D + d];
      const float wu0 = w_l2m1[row + d], wu1 = w_l2m1[row + D + d];
      const float wt0 = w_l2m2[row + d], wt1 = w_l2m2[row + D + d];
      const float u0 = Su[k],   u1 = Su[128 + k];
      const float v0 = Sum1[k], v1 = Sum1[128 + k];
      const float t0 = Sum2[k], t1 = Sum2[128 + k];
      xo00 = fmaf(u0, wv0, xo00); xo10 = fmaf(u0, wv1, xo10);
      xo01 = fmaf(u1, wv0, xo01); xo11 = fmaf(u1, wv1, xo11);
      q100 = fmaf(v0, wu0, q100); q110 = fmaf(v0, wu1, q110);
      q101 = fmaf(v1, wu0, q101); q111 = fmaf(v1, wu1, q111);
      q200 = fmaf(t0, wt0, q200); q210 = fmaf(t0, wt1, q210);
      q201 = fmaf(t1, wt0, q201); q211 = fmaf(t1, wt1, q211);
    }

    // ---- rotate back to global frame, accumulate over edges ----
    BACKROT_EDGE(0, Ra00,Ra01,Ra02,Ra10,Ra11,Ra12,Ra20,Ra21,Ra22,
                 xo00, xo10, zo0, q200, q100, p00, q110, q210);
    BACKROT_EDGE(1, Rb00,Rb01,Rb02,Rb10,Rb11,Rb12,Rb20,Rb21,Rb22,
                 xo01, xo11, zo1, q201, q101, p01, q111, q211);
    wave_sync();
  }

  // ---- cross-wave reduction into partial buffer (reuse smem) ----
  __syncthreads();
  float* red = smem;
  red[(0 * WPB + w) * D + d] = w0sum;
  red[(1 * WPB + w) * D + d] = mv0;
  red[(2 * WPB + w) * D + d] = mv1;
  red[(3 * WPB + w) * D + d] = mv2;
#pragma unroll
  for (int c = 0; c < 5; ++c) red[((4 + c) * WPB + w) * D + d] = mt[c];
  __syncthreads();
  float* pout = pws + bid * (9 * D);
  for (int idx = tid; idx < 9 * D; idx += NTHREADS) {
    const int a = idx >> 6, dd = idx & 63;
    float s = 0.f;
#pragma unroll
    for (int ww = 0; ww < WPB; ++ww) s += red[(a * WPB + ww) * D + dd];
    pout[idx] = s;
  }
}

// Kernel 2: reduce jsplit partials, scalar-path epilogue, LayerNorm, write out.
__global__ void __launch_bounds__(64) so2_epilogue_kernel(
    const float* __restrict__ node_scalar,
    const float* __restrict__ w_l0,
    const float* __restrict__ w_out,
    const float* __restrict__ b_out,
    const float* __restrict__ g_s,
    const float* __restrict__ beta_s,
    const float* __restrict__ g_v,
    const float* __restrict__ beta_v,
    const float* __restrict__ g_t,
    const float* __restrict__ beta_t,
    const float* __restrict__ pws,
    int jsplit,
    float* __restrict__ out)
{
  __shared__ float sf[9 * D];
  __shared__ float sns[D];
  __shared__ float stmp[D];

  const int bi = blockIdx.x;
  const int d = threadIdx.x;

  float f0 = 0.f;
#pragma unroll
  for (int a = 0; a < 9; ++a) {
    float s = 0.f;
    for (int sp = 0; sp < jsplit; ++sp)
      s += pws[((bi * jsplit + sp) * 9 + a) * D + d];
    sf[a * D + d] = s;
    if (a == 0) f0 = s;
  }
  sns[d] = node_scalar[bi * D + d];
  __syncthreads();

  float s0 = 0.f;
#pragma unroll 8
  for (int k = 0; k < D; ++k) s0 = fmaf(sns[k], w_l0[k * D + d], s0);
  stmp[d] = s0 * f0;
  __syncthreads();

  float pre = b_out[d];
#pragma unroll 8
  for (int k = 0; k < D; ++k) pre = fmaf(stmp[k], w_out[k * D + d], pre);

  for (int r = 0; r < 9; ++r) {
    const float x = (r == 0) ? pre : sf[r * D + d];
    float s = x;
#pragma unroll
    for (int off = 32; off > 0; off >>= 1) s += __shfl_xor(s, off, 64);
    const float mu = s * (1.f / 64.f);
    const float xm = x - mu;
    float v = xm * xm;
#pragma unroll
    for (int off = 32; off > 0; off >>= 1) v += __shfl_xor(v, off, 64);
    const float var = v * (1.f / 64.f);
    const float rstd = rsqrtf(var + 1e-5f);
    float g, be;
    int off_out;
    if (r == 0)      { g = g_s[d]; be = beta_s[d]; off_out = bi * D + d; }
    else if (r < 4)  { g = g_v[d]; be = beta_v[d]; off_out = 16384 + (bi * 3 + (r - 1)) * D + d; }
    else             { g = g_t[d]; be = beta_t[d]; off_out = 65536 + (bi * 5 + (r - 4)) * D + d; }
    out[off_out] = xm * rstd * g + be;
  }
}

extern "C" void kernel_launch(void* const* d_in, const int* in_sizes, int n_in,
                              void* d_out, int out_size, void* d_ws, size_t ws_size,
                              hipStream_t stream) {
  const float* p[24];
  for (int i = 0; i < 24; ++i) p[i] = (const float*)d_in[i];
  float* pws = (float*)d_ws;

  int jsplit = 4;
  while (jsplit > 1 && ws_size < (size_t)(256 * jsplit) * 9 * D * sizeof(float))
    jsplit >>= 1;

  so2_partial_kernel<<<dim3(256 * jsplit), dim3(NTHREADS), 0, stream>>>(
      p[1], p[2], p[3], p[4], p[5], p[6], p[7], p[8], p[9],
      p[11], p[12], p[13], p[14], p[15],
      pws, jsplit);

  so2_epilogue_kernel<<<dim3(256), dim3(64), 0, stream>>>(
      p[0], p[10], p[16], p[17], p[18], p[19], p[20], p[21], p[22], p[23],
      pws, jsplit, (float*)d_out);
}

// Round 9
// 132.574 us; speedup vs baseline: 4.9521x; 1.2351x over previous
//
#include <hip/hip_runtime.h>
#include <hip/hip_bf16.h>
#include <math.h>

#define D 64
#define NNODE 128

typedef __attribute__((ext_vector_type(8))) short short8;
typedef __attribute__((ext_vector_type(4))) float f32x4;

#define MFMA_B16(a,b,c) __builtin_amdgcn_mfma_f32_16x16x32_bf16((a),(b),(c),0,0,0)

// weight pack offsets (in shorts): layout [ntile][kfrag][lane(64)][jj(8)]
#define OFF_WR1   0        // 32x64  : KF=1, NT=4   -> 2048
#define OFF_WR2   2048     // 64x192 : KF=2, NT=12  -> 12288
#define OFF_L1M0  14336    // 64x64  : KF=2, NT=4   -> 4096
#define OFF_L1M1  18432    // 128x128: KF=4, NT=8   -> 16384
#define OFF_L2M0  34816
#define OFF_L2M1  38912
#define OFF_L2M2  55296
#define PACK_SHORTS 71680
#define PART_OFF  147456   // bytes; partials (f32) start here in d_ws

__device__ __forceinline__ unsigned short f2bf(float f) {
  unsigned int u = __float_as_uint(f);
  u += 0x7FFFu + ((u >> 16) & 1u);
  return (unsigned short)(u >> 16);
}
__device__ __forceinline__ float bf2f(unsigned short s) {
  return __uint_as_float(((unsigned int)s) << 16);
}

// Repack one f32 matrix [K][N] into bf16 B-fragment order for 16x16x32 mfma:
// dst[((n*KF + f)*64 + lane)*8 + jj] = W[f*32 + (lane>>4)*8 + jj][n*16 + (lane&15)]
__global__ void pack_kernel(const float* __restrict__ src, short* __restrict__ dst,
                            int K, int N) {
  int idx = blockIdx.x * 256 + threadIdx.x;
  if (idx >= K * N) return;
  int k = idx / N, c = idx - k * N;
  int n = c >> 4, f = k >> 5;
  int lane = (((k >> 3) & 3) << 4) | (c & 15);
  int jj = k & 7;
  int KF = K >> 5;
  dst[(((n * KF + f) << 9) + (lane << 3)) + jj] = (short)f2bf(src[idx]);
}

// Main kernel: block = 256 threads (4 waves), handles (b,i, split) -> 8/ts tiles
// of 16 edges each. All 128 j processed; masked edges have zero gates.
__global__ void __launch_bounds__(256) so2_mfma_kernel(
    const float* __restrict__ node_vec,
    const float* __restrict__ node_tensor,
    const float* __restrict__ rbf,
    const float* __restrict__ r_hat,
    const float* __restrict__ amask,
    const float* __restrict__ b_r1,
    const float* __restrict__ b_r2,
    const short* __restrict__ wpack,
    float* __restrict__ partial,
    int ts)
{
  // LDS: staging bf16 (swizzled rows), gates bf16, R/D2 f32, accumulators f32
  __shared__ __align__(16) short sUz[16 * 64];    // also aliases H (phase A/B)
  __shared__ __align__(16) short sUxy[16 * 128];
  __shared__ __align__(16) short sTm0[16 * 64];
  __shared__ __align__(16) short sTm1[16 * 128];
  __shared__ __align__(16) short sTm2[16 * 128];
  __shared__ __align__(16) short sGate[16 * 128]; // cols 0-63 = w1, 64-127 = w2
  __shared__ float sRD2[16][34];                  // 0-24: D2[c][v]; 25-33: R
  __shared__ float sMask[16];
  __shared__ float sAcc[9 * 64];                  // w0,mv0-2,mt0-4

  const int bid = blockIdx.x;
  const int bi  = bid / ts;
  const int sp  = bid - bi * ts;
  const int tpb = 8 / ts;
  const int t0  = sp * tpb;
  const int tid = threadIdx.x;
  const int w   = tid >> 6;    // wave 0..3
  const int l   = tid & 63;
  const int lr  = l & 15;      // fragment row/col id
  const int lg  = l >> 4;      // k-group
  const int d   = l;           // channel for FE

  for (int i = tid; i < 576; i += 256) sAcc[i] = 0.f;

  const float nv0 = node_vec[(bi * 3 + 0) * D + d];
  const float nv1 = node_vec[(bi * 3 + 1) * D + d];
  const float nv2 = node_vec[(bi * 3 + 2) * D + d];
  const float nt0 = node_tensor[(bi * 5 + 0) * D + d];
  const float nt1 = node_tensor[(bi * 5 + 1) * D + d];
  const float nt2 = node_tensor[(bi * 5 + 2) * D + d];
  const float nt3 = node_tensor[(bi * 5 + 3) * D + d];
  const float nt4 = node_tensor[(bi * 5 + 4) * D + d];

  __syncthreads();

  // A-fragment LDS read (bf16, swizzled): row = lr, k = kf*32 + lg*8
#define LDA64(arr, kf)  (*reinterpret_cast<const short8*>(&(arr)[((lr << 6) + (kf) * 32 + (lg << 3)) ^ ((lr & 7) << 3)]))
#define LDA128(arr, kf) (*reinterpret_cast<const short8*>(&(arr)[((lr << 7) + (kf) * 32 + (lg << 3)) ^ ((lr & 7) << 3)]))
#define LDB(off, nt, KF, kf) (*reinterpret_cast<const short8*>(&wpack[(off) + (((nt) * (KF) + (kf)) << 9) + (l << 3)]))

  for (int tt = 0; tt < tpb; ++tt) {
    const int t = t0 + tt;
    const int ebase = bi * NNODE + t * 16;

    if (tid < 16) sMask[tid] = amask[ebase + tid];

    // ---- Phase A: H = silu(RBF @ w_r1 + b_r1) -> sUz (as H) ----
    {
      const float* rp = rbf + (size_t)(ebase + lr) * 32 + lg * 8;
      const float4 ra = *(const float4*)rp;
      const float4 rb = *(const float4*)(rp + 4);
      short8 a;
      a[0] = (short)f2bf(ra.x); a[1] = (short)f2bf(ra.y);
      a[2] = (short)f2bf(ra.z); a[3] = (short)f2bf(ra.w);
      a[4] = (short)f2bf(rb.x); a[5] = (short)f2bf(rb.y);
      a[6] = (short)f2bf(rb.z); a[7] = (short)f2bf(rb.w);
      f32x4 c = {0.f, 0.f, 0.f, 0.f};
      c = MFMA_B16(a, LDB(OFF_WR1, w, 1, 0), c);
      const int cc = w * 16 + lr;
      const float bias = b_r1[cc];
#pragma unroll
      for (int q = 0; q < 4; ++q) {
        const int rr = lg * 4 + q;
        float hv = c[q] + bias;
        hv = hv / (1.f + expf(-hv));
        sUz[((rr << 6) + cc) ^ ((rr & 7) << 3)] = (short)f2bf(hv);
      }
    }
    __syncthreads();

    // ---- Phase B: G = (H @ w_r2 + b_r2) * mask -> w0sum + gates ----
#pragma unroll
    for (int nbi = 0; nbi < 3; ++nbi) {
      const int nb = w + nbi * 4;
      f32x4 c = {0.f, 0.f, 0.f, 0.f};
#pragma unroll
      for (int kf = 0; kf < 2; ++kf)
        c = MFMA_B16(LDA64(sUz, kf), LDB(OFF_WR2, nb, 2, kf), c);
      const float bias = b_r2[nb * 16 + lr];
      if (nbi == 0) {
        float pw = 0.f;
#pragma unroll
        for (int q = 0; q < 4; ++q) { const int rr = lg * 4 + q; pw += sMask[rr] * (c[q] + bias); }
        pw += __shfl_xor(pw, 16);
        pw += __shfl_xor(pw, 32);
        if (l < 16) sAcc[w * 16 + l] += pw;
      } else {
        const int gc = (nb - 4) * 16 + lr;
#pragma unroll
        for (int q = 0; q < 4; ++q) {
          const int rr = lg * 4 + q;
          sGate[((rr << 7) + gc) ^ ((rr & 7) << 3)] = (short)f2bf((c[q] + bias) * sMask[rr]);
        }
      }
    }
    __syncthreads();

    // ---- Front-end: wave w handles edges 4w..4w+3 (verified round-8 math) ----
#pragma unroll 1
    for (int n = 0; n < 4; ++n) {
      const int et = 4 * w + n;
      const int e = ebase + et;
      const float rx = r_hat[e * 3 + 0], ry = r_hat[e * 3 + 1], rz = r_hat[e * 3 + 2];
      const bool use_x = fabsf(rz) > 0.9f;
      const float fx = use_x ? 0.f : 1.f;
      const float fz = use_x ? 1.f : 0.f;
      const float proj = fx * rx + fz * rz;
      float x0 = fx - proj * rx, x1 = -proj * ry, x2 = fz - proj * rz;
      const float invn = 1.f / (sqrtf(x0 * x0 + x1 * x1 + x2 * x2) + 1e-8f);
      x0 *= invn; x1 *= invn; x2 *= invn;
      const float y0 = ry * x2 - rz * x1;
      const float y1 = rz * x0 - rx * x2;
      const float y2 = rx * x1 - ry * x0;
      float D2m[5][5];
      {
        const float aa = 0.70710678118654752f;
        float Rv[5][3];
        Rv[0][0] = x0; Rv[0][1] = x1; Rv[0][2] = x2;
        Rv[2][0] = rx; Rv[2][1] = ry; Rv[2][2] = rz;
        Rv[1][0] = aa * (y0 + rx); Rv[1][1] = aa * (y1 + ry); Rv[1][2] = aa * (y2 + rz);
        Rv[3][0] = aa * (x0 + y0); Rv[3][1] = aa * (x1 + y1); Rv[3][2] = aa * (x2 + y2);
        Rv[4][0] = aa * (x0 + rx); Rv[4][1] = aa * (x1 + ry); Rv[4][2] = aa * (x2 + rz);
        float Ap[5][5];
        const float s3 = 1.7320508075688772f;
#pragma unroll
        for (int k5 = 0; k5 < 5; ++k5) {
          const float X = Rv[k5][0], Y = Rv[k5][1], Z = Rv[k5][2];
          Ap[k5][0] = s3 * X * Z;
          Ap[k5][1] = s3 * X * Y;
          Ap[k5][2] = Y * Y - 0.5f * (X * X + Z * Z);
          Ap[k5][3] = s3 * Y * Z;
          Ap[k5][4] = 0.5f * s3 * (Z * Z - X * X);
        }
        const float tc = 0.57735026918962576f;
#pragma unroll
        for (int c = 0; c < 5; ++c) {
          D2m[c][0] = tc * (2.f * Ap[4][c] - Ap[0][c] - Ap[2][c]);
          D2m[c][1] = tc * (Ap[2][c] + 2.f * Ap[3][c]);
          D2m[c][2] = -(Ap[0][c] + Ap[2][c]);
          D2m[c][3] = tc * (Ap[0][c] + 2.f * Ap[1][c]);
          D2m[c][4] = tc * (Ap[2][c] - Ap[0][c]);
        }
      }
      // stash D2 + R for the phase-C epilogue (single-lane predicated writes)
#pragma unroll
      for (int c = 0; c < 5; ++c)
#pragma unroll
        for (int v = 0; v < 5; ++v)
          if (l == c * 5 + v) sRD2[et][c * 5 + v] = D2m[c][v];
      if (l == 25) sRD2[et][25] = x0;
      if (l == 26) sRD2[et][26] = y0;
      if (l == 27) sRD2[et][27] = rx;
      if (l == 28) sRD2[et][28] = x1;
      if (l == 29) sRD2[et][29] = y1;
      if (l == 30) sRD2[et][30] = ry;
      if (l == 31) sRD2[et][31] = x2;
      if (l == 32) sRD2[et][32] = y2;
      if (l == 33) sRD2[et][33] = rz;
      // gates (bf16 broadcasts)
      const int gb = et << 7;
      const int sw = (et & 7) << 3;
      const float a1   = bf2f((unsigned short)sGate[(gb + d) ^ sw]);
      const float a2   = bf2f((unsigned short)sGate[(gb + 64 + d) ^ sw]);
      const float a1lo = bf2f((unsigned short)sGate[(gb + (d >> 1)) ^ sw]);
      const float a1hi = bf2f((unsigned short)sGate[(gb + 32 + (d >> 1)) ^ sw]);
      const float a2lo = bf2f((unsigned short)sGate[(gb + 64 + (d >> 1)) ^ sw]);
      const float a2hi = bf2f((unsigned short)sGate[(gb + 96 + (d >> 1)) ^ sw]);
      // local-frame features
      const float vl0 = x0 * nv0 + y0 * nv1 + rx * nv2;
      const float vl1 = x1 * nv0 + y1 * nv1 + ry * nv2;
      const float vl2 = x2 * nv0 + y2 * nv1 + rz * nv2;
      const float tl0 = D2m[0][0]*nt0 + D2m[0][1]*nt1 + D2m[0][2]*nt2 + D2m[0][3]*nt3 + D2m[0][4]*nt4;
      const float tl1 = D2m[1][0]*nt0 + D2m[1][1]*nt1 + D2m[1][2]*nt2 + D2m[1][3]*nt3 + D2m[1][4]*nt4;
      const float tl2 = D2m[2][0]*nt0 + D2m[2][1]*nt1 + D2m[2][2]*nt2 + D2m[2][3]*nt3 + D2m[2][4]*nt4;
      const float tl3 = D2m[3][0]*nt0 + D2m[3][1]*nt1 + D2m[3][2]*nt2 + D2m[3][3]*nt3 + D2m[3][4]*nt4;
      const float tl4 = D2m[4][0]*nt0 + D2m[4][1]*nt1 + D2m[4][2]*nt2 + D2m[4][3]*nt3 + D2m[4][4]*nt4;
      // stage gated inputs (bf16, swizzled)
      const int b64 = et << 6;
      sUz [(b64 + d) ^ sw]        = (short)f2bf(vl2 * a1);
      sUxy[(gb + d) ^ sw]         = (short)f2bf(vl0 * a1lo);
      sUxy[(gb + 64 + d) ^ sw]    = (short)f2bf(vl1 * a1hi);
      sTm0[(b64 + d) ^ sw]        = (short)f2bf(tl2 * a2);
      sTm1[(gb + d) ^ sw]         = (short)f2bf(tl1 * a2lo);
      sTm1[(gb + 64 + d) ^ sw]    = (short)f2bf(tl3 * a2hi);
      sTm2[(gb + d) ^ sw]         = (short)f2bf(tl0 * a2lo);
      sTm2[(gb + 64 + d) ^ sw]    = (short)f2bf(tl4 * a2hi);
    }
    __syncthreads();

    // ---- Phase C: five GEMMs; wave w owns output cols [16w,16w+16) (+64 twin) ----
    {
      f32x4 z   = {0.f,0.f,0.f,0.f}, p0  = {0.f,0.f,0.f,0.f};
      f32x4 xya = {0.f,0.f,0.f,0.f}, xyb = {0.f,0.f,0.f,0.f};
      f32x4 p1a = {0.f,0.f,0.f,0.f}, p1b = {0.f,0.f,0.f,0.f};
      f32x4 p2a = {0.f,0.f,0.f,0.f}, p2b = {0.f,0.f,0.f,0.f};
#pragma unroll
      for (int kf = 0; kf < 2; ++kf) {
        z  = MFMA_B16(LDA64(sUz,  kf), LDB(OFF_L1M0, w, 2, kf), z);
        p0 = MFMA_B16(LDA64(sTm0, kf), LDB(OFF_L2M0, w, 2, kf), p0);
      }
#pragma unroll
      for (int kf = 0; kf < 4; ++kf) {
        const short8 ax = LDA128(sUxy, kf);
        xya = MFMA_B16(ax, LDB(OFF_L1M1, w,     4, kf), xya);
        xyb = MFMA_B16(ax, LDB(OFF_L1M1, w + 4, 4, kf), xyb);
        const short8 a1f = LDA128(sTm1, kf);
        p1a = MFMA_B16(a1f, LDB(OFF_L2M1, w,     4, kf), p1a);
        p1b = MFMA_B16(a1f, LDB(OFF_L2M1, w + 4, 4, kf), p1b);
        const short8 a2f = LDA128(sTm2, kf);
        p2a = MFMA_B16(a2f, LDB(OFF_L2M2, w,     4, kf), p2a);
        p2b = MFMA_B16(a2f, LDB(OFF_L2M2, w + 4, 4, kf), p2b);
      }
      // back-rotate + accumulate over the tile's 16 edges
      float pv0 = 0.f, pv1 = 0.f, pv2 = 0.f;
      float pm[5] = {0.f, 0.f, 0.f, 0.f, 0.f};
#pragma unroll
      for (int q = 0; q < 4; ++q) {
        const int rr = lg * 4 + q;
        const float* Rr = sRD2[rr];
        const float xa = xya[q], xb = xyb[q], zz = z[q];
        pv0 += Rr[25] * xa + Rr[28] * xb + Rr[31] * zz;
        pv1 += Rr[26] * xa + Rr[29] * xb + Rr[32] * zz;
        pv2 += Rr[27] * xa + Rr[30] * xb + Rr[33] * zz;
        const float m2a = p2a[q], m1a = p1a[q], m0 = p0[q], m1b = p1b[q], m2b = p2b[q];
#pragma unroll
        for (int p = 0; p < 5; ++p)
          pm[p] += Rr[0 * 5 + p] * m2a + Rr[1 * 5 + p] * m1a + Rr[2 * 5 + p] * m0
                 + Rr[3 * 5 + p] * m1b + Rr[4 * 5 + p] * m2b;
      }
      pv0 += __shfl_xor(pv0, 16); pv0 += __shfl_xor(pv0, 32);
      pv1 += __shfl_xor(pv1, 16); pv1 += __shfl_xor(pv1, 32);
      pv2 += __shfl_xor(pv2, 16); pv2 += __shfl_xor(pv2, 32);
#pragma unroll
      for (int p = 0; p < 5; ++p) { pm[p] += __shfl_xor(pm[p], 16); pm[p] += __shfl_xor(pm[p], 32); }
      if (l < 16) {
        const int cc = w * 16 + l;
        sAcc[1 * 64 + cc] += pv0;
        sAcc[2 * 64 + cc] += pv1;
        sAcc[3 * 64 + cc] += pv2;
#pragma unroll
        for (int p = 0; p < 5; ++p) sAcc[(4 + p) * 64 + cc] += pm[p];
      }
    }
    __syncthreads();
  }

  for (int i = tid; i < 576; i += 256) partial[(size_t)bid * 576 + i] = sAcc[i];
#undef LDA64
#undef LDA128
#undef LDB
}

// Kernel 2 (verified in round 8): reduce partials, scalar epilogue, LayerNorm.
__global__ void __launch_bounds__(64) so2_epilogue_kernel(
    const float* __restrict__ node_scalar,
    const float* __restrict__ w_l0,
    const float* __restrict__ w_out,
    const float* __restrict__ b_out,
    const float* __restrict__ g_s,
    const float* __restrict__ beta_s,
    const float* __restrict__ g_v,
    const float* __restrict__ beta_v,
    const float* __restrict__ g_t,
    const float* __restrict__ beta_t,
    const float* __restrict__ pws,
    int jsplit,
    float* __restrict__ out)
{
  __shared__ float sf[9 * D];
  __shared__ float sns[D];
  __shared__ float stmp[D];

  const int bi = blockIdx.x;
  const int d = threadIdx.x;

  float f0 = 0.f;
#pragma unroll
  for (int a = 0; a < 9; ++a) {
    float s = 0.f;
    for (int sp = 0; sp < jsplit; ++sp)
      s += pws[((bi * jsplit + sp) * 9 + a) * D + d];
    sf[a * D + d] = s;
    if (a == 0) f0 = s;
  }
  sns[d] = node_scalar[bi * D + d];
  __syncthreads();

  float s0 = 0.f;
#pragma unroll 8
  for (int k = 0; k < D; ++k) s0 = fmaf(sns[k], w_l0[k * D + d], s0);
  stmp[d] = s0 * f0;
  __syncthreads();

  float pre = b_out[d];
#pragma unroll 8
  for (int k = 0; k < D; ++k) pre = fmaf(stmp[k], w_out[k * D + d], pre);

  for (int r = 0; r < 9; ++r) {
    const float x = (r == 0) ? pre : sf[r * D + d];
    float s = x;
#pragma unroll
    for (int off = 32; off > 0; off >>= 1) s += __shfl_xor(s, off, 64);
    const float mu = s * (1.f / 64.f);
    const float xm = x - mu;
    float v = xm * xm;
#pragma unroll
    for (int off = 32; off > 0; off >>= 1) v += __shfl_xor(v, off, 64);
    const float var = v * (1.f / 64.f);
    const float rstd = rsqrtf(var + 1e-5f);
    float g, be;
    int off_out;
    if (r == 0)      { g = g_s[d]; be = beta_s[d]; off_out = bi * D + d; }
    else if (r < 4)  { g = g_v[d]; be = beta_v[d]; off_out = 16384 + (bi * 3 + (r - 1)) * D + d; }
    else             { g = g_t[d]; be = beta_t[d]; off_out = 65536 + (bi * 5 + (r - 4)) * D + d; }
    out[off_out] = xm * rstd * g + be;
  }
}

extern "C" void kernel_launch(void* const* d_in, const int* in_sizes, int n_in,
                              void* d_out, int out_size, void* d_ws, size_t ws_size,
                              hipStream_t stream) {
  const float* p[24];
  for (int i = 0; i < 24; ++i) p[i] = (const float*)d_in[i];
  short* wpack = (short*)d_ws;
  float* partial = (float*)((char*)d_ws + PART_OFF);

  int ts = 4;
  while (ts > 1 && ws_size < (size_t)PART_OFF + (size_t)256 * ts * 576 * sizeof(float))
    ts >>= 1;

  // pack weights -> bf16 B-fragment order
  pack_kernel<<<dim3(8),  dim3(256), 0, stream>>>(p[6],  wpack + OFF_WR1,  32, 64);
  pack_kernel<<<dim3(48), dim3(256), 0, stream>>>(p[8],  wpack + OFF_WR2,  64, 192);
  pack_kernel<<<dim3(16), dim3(256), 0, stream>>>(p[11], wpack + OFF_L1M0, 64, 64);
  pack_kernel<<<dim3(64), dim3(256), 0, stream>>>(p[12], wpack + OFF_L1M1, 128, 128);
  pack_kernel<<<dim3(16), dim3(256), 0, stream>>>(p[13], wpack + OFF_L2M0, 64, 64);
  pack_kernel<<<dim3(64), dim3(256), 0, stream>>>(p[14], wpack + OFF_L2M1, 128, 128);
  pack_kernel<<<dim3(64), dim3(256), 0, stream>>>(p[15], wpack + OFF_L2M2, 128, 128);

  so2_mfma_kernel<<<dim3(256 * ts), dim3(256), 0, stream>>>(
      p[1], p[2], p[3], p[4], p[5], p[7], p[9], wpack, partial, ts);

  so2_epilogue_kernel<<<dim3(256), dim3(64), 0, stream>>>(
      p[0], p[10], p[16], p[17], p[18], p[19], p[20], p[21], p[22], p[23],
      partial, ts, (float*)d_out);
}

// Round 11
// 94.605 us; speedup vs baseline: 6.9396x; 1.4013x over previous
//
#include <hip/hip_runtime.h>
#include <hip/hip_bf16.h>
#include <math.h>

#define D 64
#define NNODE 128

typedef __attribute__((ext_vector_type(8))) short short8;
typedef __attribute__((ext_vector_type(4))) float f32x4;

#define MFMA_B16(a,b,c) __builtin_amdgcn_mfma_f32_16x16x32_bf16((a),(b),(c),0,0,0)

// weight pack offsets (in shorts): layout [ntile][kfrag][lane(64)][jj(8)]
#define OFF_WR1   0        // 32x64  : KF=1, NT=4   -> 2048
#define OFF_WR2   2048     // 64x192 : KF=2, NT=12  -> 12288
#define OFF_L1M0  14336    // 64x64  : KF=2, NT=4   -> 4096
#define OFF_L1M1  18432    // 128x128: KF=4, NT=8   -> 16384
#define OFF_L2M0  34816
#define OFF_L2M1  38912
#define OFF_L2M2  55296
#define PACK_SHORTS 71680
#define PART_OFF  147456   // bytes; partials (f32) start here in d_ws

__device__ __forceinline__ unsigned short f2bf(float f) {
  unsigned int u = __float_as_uint(f);
  u += 0x7FFFu + ((u >> 16) & 1u);
  return (unsigned short)(u >> 16);
}
__device__ __forceinline__ float bf2f(unsigned short s) {
  return __uint_as_float(((unsigned int)s) << 16);
}

// One fused pack: all 7 f32 matrices -> bf16 B-fragment order for 16x16x32 mfma.
// dst[off + ((n*KF + f)*64 + lane)*8 + jj] = W[f*32 + (lane>>4)*8 + jj][n*16 + (lane&15)]
__global__ void pack_all_kernel(const float* __restrict__ wr1, const float* __restrict__ wr2,
                                const float* __restrict__ l1m0, const float* __restrict__ l1m1,
                                const float* __restrict__ l2m0, const float* __restrict__ l2m1,
                                const float* __restrict__ l2m2, short* __restrict__ dst) {
  int idx = blockIdx.x * 256 + threadIdx.x;
  const float* src; int K, N, off, loc;
  if (idx < 2048)       { src = wr1;  K = 32;  N = 64;  off = OFF_WR1;  loc = idx; }
  else if (idx < 14336) { src = wr2;  K = 64;  N = 192; off = OFF_WR2;  loc = idx - 2048; }
  else if (idx < 18432) { src = l1m0; K = 64;  N = 64;  off = OFF_L1M0; loc = idx - 14336; }
  else if (idx < 34816) { src = l1m1; K = 128; N = 128; off = OFF_L1M1; loc = idx - 18432; }
  else if (idx < 38912) { src = l2m0; K = 64;  N = 64;  off = OFF_L2M0; loc = idx - 34816; }
  else if (idx < 55296) { src = l2m1; K = 128; N = 128; off = OFF_L2M1; loc = idx - 38912; }
  else if (idx < 71680) { src = l2m2; K = 128; N = 128; off = OFF_L2M2; loc = idx - 55296; }
  else return;
  int k = loc / N, c = loc - k * N;
  int n = c >> 4, f = k >> 5;
  int lane = (((k >> 3) & 3) << 4) | (c & 15);
  int jj = k & 7;
  int KF = K >> 5;
  dst[off + (((n * KF + f) << 9) + (lane << 3)) + jj] = (short)f2bf(src[loc]);
}

// Main kernel: 256 threads (4 waves) per (b,i,split); 8/ts tiles of 16 edges.
__global__ void __launch_bounds__(256, 4) so2_mfma_kernel(
    const float* __restrict__ node_vec,
    const float* __restrict__ node_tensor,
    const float* __restrict__ rbf,
    const float* __restrict__ r_hat,
    const float* __restrict__ amask,
    const float* __restrict__ b_r1,
    const float* __restrict__ b_r2,
    const short* __restrict__ wpack,
    float* __restrict__ partial,
    int ts)
{
  __shared__ __align__(16) short sUz[16 * 64];    // aliases H in phases A/B
  __shared__ __align__(16) short sUxy[16 * 128];
  __shared__ __align__(16) short sTm0[16 * 64];
  __shared__ __align__(16) short sTm1[16 * 128];
  __shared__ __align__(16) short sTm2[16 * 128];
  __shared__ __align__(16) short sGate[16 * 128]; // cols 0-63 = w1, 64-127 = w2
  __shared__ __align__(16) float sRD2[16][56];    // [c*8+v]=D2[c][v]; [40..48]=x0,y0,rx,x1,y1,ry,x2,y2,rz
  __shared__ float sMask[16];
  __shared__ float sAcc[9 * 64];

  const int bid = blockIdx.x;
  const int bi  = bid / ts;
  const int sp  = bid - bi * ts;
  const int tpb = 8 / ts;
  const int t0  = sp * tpb;
  const int tid = threadIdx.x;
  const int w   = tid >> 6;
  const int l   = tid & 63;
  const int lr  = l & 15;
  const int lg  = l >> 4;
  const int d   = l;

  for (int i = tid; i < 576; i += 256) sAcc[i] = 0.f;

  const float nv0 = node_vec[(bi * 3 + 0) * D + d];
  const float nv1 = node_vec[(bi * 3 + 1) * D + d];
  const float nv2 = node_vec[(bi * 3 + 2) * D + d];
  const float nt0 = node_tensor[(bi * 5 + 0) * D + d];
  const float nt1 = node_tensor[(bi * 5 + 1) * D + d];
  const float nt2 = node_tensor[(bi * 5 + 2) * D + d];
  const float nt3 = node_tensor[(bi * 5 + 3) * D + d];
  const float nt4 = node_tensor[(bi * 5 + 4) * D + d];

  __syncthreads();

#define LDA64(arr, kf)  (*reinterpret_cast<const short8*>(&(arr)[((lr << 6) + (kf) * 32 + (lg << 3)) ^ ((lr & 7) << 3)]))
#define LDA128(arr, kf) (*reinterpret_cast<const short8*>(&(arr)[((lr << 7) + (kf) * 32 + (lg << 3)) ^ ((lr & 7) << 3)]))
#define LDB(off, nt, KF, kf) (*reinterpret_cast<const short8*>(&wpack[(off) + (((nt) * (KF) + (kf)) << 9) + (l << 3)]))

  for (int tt = 0; tt < tpb; ++tt) {
    const int t = t0 + tt;
    const int ebase = bi * NNODE + t * 16;

    if (tid < 16) sMask[tid] = amask[ebase + tid];

    // ---- Phase A: H = silu(RBF @ w_r1 + b_r1) -> sUz ----
    {
      const float* rp = rbf + (size_t)(ebase + lr) * 32 + lg * 8;
      const float4 ra = *(const float4*)rp;
      const float4 rb = *(const float4*)(rp + 4);
      short8 a;
      a[0] = (short)f2bf(ra.x); a[1] = (short)f2bf(ra.y);
      a[2] = (short)f2bf(ra.z); a[3] = (short)f2bf(ra.w);
      a[4] = (short)f2bf(rb.x); a[5] = (short)f2bf(rb.y);
      a[6] = (short)f2bf(rb.z); a[7] = (short)f2bf(rb.w);
      f32x4 c = {0.f, 0.f, 0.f, 0.f};
      c = MFMA_B16(a, LDB(OFF_WR1, w, 1, 0), c);
      const int cc = w * 16 + lr;
      const float bias = b_r1[cc];
#pragma unroll
      for (int q = 0; q < 4; ++q) {
        const int rr = lg * 4 + q;
        float hv = c[q] + bias;
        hv = hv / (1.f + expf(-hv));
        sUz[((rr << 6) + cc) ^ ((rr & 7) << 3)] = (short)f2bf(hv);
      }
    }
    __syncthreads();

    // ---- Phase B: G = (H @ w_r2 + b_r2) * mask -> w0sum + gates ----
#pragma unroll
    for (int nbi = 0; nbi < 3; ++nbi) {
      const int nb = w + nbi * 4;
      f32x4 c = {0.f, 0.f, 0.f, 0.f};
#pragma unroll
      for (int kf = 0; kf < 2; ++kf)
        c = MFMA_B16(LDA64(sUz, kf), LDB(OFF_WR2, nb, 2, kf), c);
      const float bias = b_r2[nb * 16 + lr];
      if (nbi == 0) {
        float pw = 0.f;
#pragma unroll
        for (int q = 0; q < 4; ++q) { const int rr = lg * 4 + q; pw += sMask[rr] * (c[q] + bias); }
        pw += __shfl_xor(pw, 16);
        pw += __shfl_xor(pw, 32);
        if (l < 16) sAcc[w * 16 + l] += pw;
      } else {
        const int gc = (nb - 4) * 16 + lr;
#pragma unroll
        for (int q = 0; q < 4; ++q) {
          const int rr = lg * 4 + q;
          sGate[((rr << 7) + gc) ^ ((rr & 7) << 3)] = (short)f2bf((c[q] + bias) * sMask[rr]);
        }
      }
    }
    __syncthreads();

    // ---- Front-end rotations: lane-parallel, edge et = 4w + (l&3) ----
    {
      const int et = 4 * w + (l & 3);
      const int e = ebase + et;
      const float rx = r_hat[e * 3 + 0], ry = r_hat[e * 3 + 1], rz = r_hat[e * 3 + 2];
      const bool use_x = fabsf(rz) > 0.9f;
      const float fx = use_x ? 0.f : 1.f;
      const float fz = use_x ? 1.f : 0.f;
      const float proj = fx * rx + fz * rz;
      float x0 = fx - proj * rx, x1 = -proj * ry, x2 = fz - proj * rz;
      const float invn = 1.f / (sqrtf(x0 * x0 + x1 * x1 + x2 * x2) + 1e-8f);
      x0 *= invn; x1 *= invn; x2 *= invn;
      const float y0 = ry * x2 - rz * x1;
      const float y1 = rz * x0 - rx * x2;
      const float y2 = rx * x1 - ry * x0;
      float D2m[5][5];
      {
        const float aa = 0.70710678118654752f;
        float Rv[5][3];
        Rv[0][0] = x0; Rv[0][1] = x1; Rv[0][2] = x2;
        Rv[2][0] = rx; Rv[2][1] = ry; Rv[2][2] = rz;
        Rv[1][0] = aa * (y0 + rx); Rv[1][1] = aa * (y1 + ry); Rv[1][2] = aa * (y2 + rz);
        Rv[3][0] = aa * (x0 + y0); Rv[3][1] = aa * (x1 + y1); Rv[3][2] = aa * (x2 + y2);
        Rv[4][0] = aa * (x0 + rx); Rv[4][1] = aa * (x1 + ry); Rv[4][2] = aa * (x2 + rz);
        float Ap[5][5];
        const float s3 = 1.7320508075688772f;
#pragma unroll
        for (int k5 = 0; k5 < 5; ++k5) {
          const float X = Rv[k5][0], Y = Rv[k5][1], Z = Rv[k5][2];
          Ap[k5][0] = s3 * X * Z;
          Ap[k5][1] = s3 * X * Y;
          Ap[k5][2] = Y * Y - 0.5f * (X * X + Z * Z);
          Ap[k5][3] = s3 * Y * Z;
          Ap[k5][4] = 0.5f * s3 * (Z * Z - X * X);
        }
        const float tc = 0.57735026918962576f;
#pragma unroll
        for (int c = 0; c < 5; ++c) {
          D2m[c][0] = tc * (2.f * Ap[4][c] - Ap[0][c] - Ap[2][c]);
          D2m[c][1] = tc * (Ap[2][c] + 2.f * Ap[3][c]);
          D2m[c][2] = -(Ap[0][c] + Ap[2][c]);
          D2m[c][3] = tc * (Ap[0][c] + 2.f * Ap[1][c]);
          D2m[c][4] = tc * (Ap[2][c] - Ap[0][c]);
        }
      }
      if (l < 4) {
        float* Rr = sRD2[et];
#pragma unroll
        for (int c = 0; c < 5; ++c) {
          *(float4*)&Rr[c * 8] = make_float4(D2m[c][0], D2m[c][1], D2m[c][2], D2m[c][3]);
          Rr[c * 8 + 4] = D2m[c][4];
        }
        *(float4*)&Rr[40] = make_float4(x0, y0, rx, x1);
        *(float4*)&Rr[44] = make_float4(y1, ry, x2, y2);
        Rr[48] = rz;
      }
    }
    asm volatile("s_waitcnt lgkmcnt(0)" ::: "memory");   // intra-wave: sRD2 rows 4w..4w+3 visible

    // ---- Staging: per-edge, R/D2 from LDS broadcasts ----
#pragma unroll 1
    for (int n = 0; n < 4; ++n) {
      const int et = 4 * w + n;
      const float* Rr = sRD2[et];
      const int gb = et << 7;
      const int sw = (et & 7) << 3;
      const float a1   = bf2f((unsigned short)sGate[(gb + d) ^ sw]);
      const float a2   = bf2f((unsigned short)sGate[(gb + 64 + d) ^ sw]);
      const float a1lo = bf2f((unsigned short)sGate[(gb + (d >> 1)) ^ sw]);
      const float a1hi = bf2f((unsigned short)sGate[(gb + 32 + (d >> 1)) ^ sw]);
      const float a2lo = bf2f((unsigned short)sGate[(gb + 64 + (d >> 1)) ^ sw]);
      const float a2hi = bf2f((unsigned short)sGate[(gb + 96 + (d >> 1)) ^ sw]);
      const float vl0 = Rr[40] * nv0 + Rr[41] * nv1 + Rr[42] * nv2;
      const float vl1 = Rr[43] * nv0 + Rr[44] * nv1 + Rr[45] * nv2;
      const float vl2 = Rr[46] * nv0 + Rr[47] * nv1 + Rr[48] * nv2;
      float tl[5];
#pragma unroll
      for (int p = 0; p < 5; ++p)
        tl[p] = Rr[p * 8 + 0] * nt0 + Rr[p * 8 + 1] * nt1 + Rr[p * 8 + 2] * nt2
              + Rr[p * 8 + 3] * nt3 + Rr[p * 8 + 4] * nt4;
      const int b64 = et << 6;
      sUz [(b64 + d) ^ sw]     = (short)f2bf(vl2 * a1);
      sUxy[(gb + d) ^ sw]      = (short)f2bf(vl0 * a1lo);
      sUxy[(gb + 64 + d) ^ sw] = (short)f2bf(vl1 * a1hi);
      sTm0[(b64 + d) ^ sw]     = (short)f2bf(tl[2] * a2);
      sTm1[(gb + d) ^ sw]      = (short)f2bf(tl[1] * a2lo);
      sTm1[(gb + 64 + d) ^ sw] = (short)f2bf(tl[3] * a2hi);
      sTm2[(gb + d) ^ sw]      = (short)f2bf(tl[0] * a2lo);
      sTm2[(gb + 64 + d) ^ sw] = (short)f2bf(tl[4] * a2hi);
    }
    __syncthreads();

    // ---- Phase C: five GEMMs; wave w owns output cols [16w,16w+16) (+64 twin) ----
    {
      f32x4 z   = {0.f,0.f,0.f,0.f}, p0  = {0.f,0.f,0.f,0.f};
      f32x4 xya = {0.f,0.f,0.f,0.f}, xyb = {0.f,0.f,0.f,0.f};
      f32x4 p1a = {0.f,0.f,0.f,0.f}, p1b = {0.f,0.f,0.f,0.f};
      f32x4 p2a = {0.f,0.f,0.f,0.f}, p2b = {0.f,0.f,0.f,0.f};
#pragma unroll
      for (int kf = 0; kf < 2; ++kf) {
        z  = MFMA_B16(LDA64(sUz,  kf), LDB(OFF_L1M0, w, 2, kf), z);
        p0 = MFMA_B16(LDA64(sTm0, kf), LDB(OFF_L2M0, w, 2, kf), p0);
      }
#pragma unroll
      for (int kf = 0; kf < 4; ++kf) {
        const short8 ax = LDA128(sUxy, kf);
        xya = MFMA_B16(ax, LDB(OFF_L1M1, w,     4, kf), xya);
        xyb = MFMA_B16(ax, LDB(OFF_L1M1, w + 4, 4, kf), xyb);
        const short8 a1f = LDA128(sTm1, kf);
        p1a = MFMA_B16(a1f, LDB(OFF_L2M1, w,     4, kf), p1a);
        p1b = MFMA_B16(a1f, LDB(OFF_L2M1, w + 4, 4, kf), p1b);
        const short8 a2f = LDA128(sTm2, kf);
        p2a = MFMA_B16(a2f, LDB(OFF_L2M2, w,     4, kf), p2a);
        p2b = MFMA_B16(a2f, LDB(OFF_L2M2, w + 4, 4, kf), p2b);
      }
      float pv0 = 0.f, pv1 = 0.f, pv2 = 0.f;
      float pm[5] = {0.f, 0.f, 0.f, 0.f, 0.f};
#pragma unroll
      for (int q = 0; q < 4; ++q) {
        const int rr = lg * 4 + q;
        const float* Rr = sRD2[rr];
        const float xa = xya[q], xb = xyb[q], zz = z[q];
        pv0 += Rr[40] * xa + Rr[43] * xb + Rr[46] * zz;
        pv1 += Rr[41] * xa + Rr[44] * xb + Rr[47] * zz;
        pv2 += Rr[42] * xa + Rr[45] * xb + Rr[48] * zz;
        const float m2a = p2a[q], m1a = p1a[q], m0 = p0[q], m1b = p1b[q], m2b = p2b[q];
#pragma unroll
        for (int p = 0; p < 5; ++p)
          pm[p] += Rr[0 * 8 + p] * m2a + Rr[1 * 8 + p] * m1a + Rr[2 * 8 + p] * m0
                 + Rr[3 * 8 + p] * m1b + Rr[4 * 8 + p] * m2b;
      }
      pv0 += __shfl_xor(pv0, 16); pv0 += __shfl_xor(pv0, 32);
      pv1 += __shfl_xor(pv1, 16); pv1 += __shfl_xor(pv1, 32);
      pv2 += __shfl_xor(pv2, 16); pv2 += __shfl_xor(pv2, 32);
#pragma unroll
      for (int p = 0; p < 5; ++p) { pm[p] += __shfl_xor(pm[p], 16); pm[p] += __shfl_xor(pm[p], 32); }
      if (l < 16) {
        const int cc = w * 16 + l;
        sAcc[1 * 64 + cc] += pv0;
        sAcc[2 * 64 + cc] += pv1;
        sAcc[3 * 64 + cc] += pv2;
#pragma unroll
        for (int p = 0; p < 5; ++p) sAcc[(4 + p) * 64 + cc] += pm[p];
      }
    }
    __syncthreads();
  }

  for (int i = tid; i < 576; i += 256) partial[(size_t)bid * 576 + i] = sAcc[i];
#undef LDA64
#undef LDA128
#undef LDB
}

// Kernel 2 (verified): reduce partials, scalar epilogue, LayerNorm.
__global__ void __launch_bounds__(64) so2_epilogue_kernel(
    const float* __restrict__ node_scalar,
    const float* __restrict__ w_l0,
    const float* __restrict__ w_out,
    const float* __restrict__ b_out,
    const float* __restrict__ g_s,
    const float* __restrict__ beta_s,
    const float* __restrict__ g_v,
    const float* __restrict__ beta_v,
    const float* __restrict__ g_t,
    const float* __restrict__ beta_t,
    const float* __restrict__ pws,
    int jsplit,
    float* __restrict__ out)
{
  __shared__ float sf[9 * D];
  __shared__ float sns[D];
  __shared__ float stmp[D];

  const int bi = blockIdx.x;
  const int d = threadIdx.x;

  float f0 = 0.f;
#pragma unroll
  for (int a = 0; a < 9; ++a) {
    float s = 0.f;
    for (int sp = 0; sp < jsplit; ++sp)
      s += pws[((bi * jsplit + sp) * 9 + a) * D + d];
    sf[a * D + d] = s;
    if (a == 0) f0 = s;
  }
  sns[d] = node_scalar[bi * D + d];
  __syncthreads();

  float s0 = 0.f;
#pragma unroll 8
  for (int k = 0; k < D; ++k) s0 = fmaf(sns[k], w_l0[k * D + d], s0);
  stmp[d] = s0 * f0;
  __syncthreads();

  float pre = b_out[d];
#pragma unroll 8
  for (int k = 0; k < D; ++k) pre = fmaf(stmp[k], w_out[k * D + d], pre);

  for (int r = 0; r < 9; ++r) {
    const float x = (r == 0) ? pre : sf[r * D + d];
    float s = x;
#pragma unroll
    for (int off = 32; off > 0; off >>= 1) s += __shfl_xor(s, off, 64);
    const float mu = s * (1.f / 64.f);
    const float xm = x - mu;
    float v = xm * xm;
#pragma unroll
    for (int off = 32; off > 0; off >>= 1) v += __shfl_xor(v, off, 64);
    const float var = v * (1.f / 64.f);
    const float rstd = rsqrtf(var + 1e-5f);
    float g, be;
    int off_out;
    if (r == 0)      { g = g_s[d]; be = beta_s[d]; off_out = bi * D + d; }
    else if (r < 4)  { g = g_v[d]; be = beta_v[d]; off_out = 16384 + (bi * 3 + (r - 1)) * D + d; }
    else             { g = g_t[d]; be = beta_t[d]; off_out = 65536 + (bi * 5 + (r - 4)) * D + d; }
    out[off_out] = xm * rstd * g + be;
  }
}

extern "C" void kernel_launch(void* const* d_in, const int* in_sizes, int n_in,
                              void* d_out, int out_size, void* d_ws, size_t ws_size,
                              hipStream_t stream) {
  const float* p[24];
  for (int i = 0; i < 24; ++i) p[i] = (const float*)d_in[i];
  short* wpack = (short*)d_ws;
  float* partial = (float*)((char*)d_ws + PART_OFF);

  int ts = 8;
  while (ts > 1 && ws_size < (size_t)PART_OFF + (size_t)256 * ts * 576 * sizeof(float))
    ts >>= 1;

  pack_all_kernel<<<dim3(280), dim3(256), 0, stream>>>(
      p[6], p[8], p[11], p[12], p[13], p[14], p[15], wpack);

  so2_mfma_kernel<<<dim3(256 * ts), dim3(256), 0, stream>>>(
      p[1], p[2], p[3], p[4], p[5], p[7], p[9], wpack, partial, ts);

  so2_epilogue_kernel<<<dim3(256), dim3(64), 0, stream>>>(
      p[0], p[10], p[16], p[17], p[18], p[19], p[20], p[21], p[22], p[23],
      partial, ts, (float*)d_out);
}